// Round 8
// baseline (472.845 us; speedup 1.0000x reference)
//
#include <hip/hip_runtime.h>
#include <stdint.h>

#define DEV __device__ __forceinline__

typedef unsigned short u16;
typedef unsigned int u32;
typedef __attribute__((ext_vector_type(8))) __bf16 bf16x8;
typedef __attribute__((ext_vector_type(4))) float f32x4;

DEV u16 f2b(float f) {
  u32 u = __float_as_uint(f);
  u32 r = (u + 0x7FFFu + ((u >> 16) & 1u)) >> 16;
  return (u16)r;
}
DEV float b2f(u16 u) { return __uint_as_float(((u32)u) << 16); }
DEV void up2(u32 u, float& a, float& b) {
  a = __uint_as_float(u << 16);
  b = __uint_as_float(u & 0xffff0000u);
}
DEV void up8(uint4 t, float* d) {
  up2(t.x, d[0], d[1]); up2(t.y, d[2], d[3]);
  up2(t.z, d[4], d[5]); up2(t.w, d[6], d[7]);
}
DEV float silu_f(float v) { return v / (1.0f + __expf(-v)); }

DEV float redmax16(float v) {
  v = fmaxf(v, __shfl_xor(v, 1));
  v = fmaxf(v, __shfl_xor(v, 2));
  v = fmaxf(v, __shfl_xor(v, 4));
  v = fmaxf(v, __shfl_xor(v, 8));
  return v;
}
DEV float redsum16(float v) {
  v += __shfl_xor(v, 1);
  v += __shfl_xor(v, 2);
  v += __shfl_xor(v, 4);
  v += __shfl_xor(v, 8);
  return v;
}

// async global -> LDS, 16B per lane. LDS dest wave-uniform base + lane*16.
DEV void gload16(const u16* g, u16* l) {
  __builtin_amdgcn_global_load_lds(
      (const __attribute__((address_space(1))) uint32_t*)(g),
      (__attribute__((address_space(3))) uint32_t*)(l), 16, 0, 0);
}

// -------- merged weight converts f32 -> bf16 --------
struct WConv {
  const float* s0; const float* s1; const float* s2; const float* s3;
  const float* s4; const float* s5; const float* s6;
  u16* d0; u16* d1; u16* d2; u16* d3; u16* d4; u16* d5; u16* d6;
};
__global__ void k_conv_all(WConv wc) {
  int i = blockIdx.x * 256 + threadIdx.x;  // float4 index, total 180224
  if (i >= 180224) return;
  const float* sp[7] = {wc.s0, wc.s1, wc.s2, wc.s3, wc.s4, wc.s5, wc.s6};
  u16* dp[7] = {wc.d0, wc.d1, wc.d2, wc.d3, wc.d4, wc.d5, wc.d6};
  const int n4[7] = {16384, 16384, 32768, 32768, 49152, 16384, 16384};
  int rem = i, seg = 0;
#pragma unroll
  for (int s = 0; s < 7; ++s) {
    if (rem < n4[s]) { seg = s; break; }
    rem -= n4[s];
  }
  float4 v = ((const float4*)sp[seg])[rem];
  u16 t[4] = {f2b(v.x), f2b(v.y), f2b(v.z), f2b(v.w)};
  *(uint2*)(dp[seg] + (rem << 2)) = *(uint2*)t;
}

// -------- block reduce (sum,sumsq) over 256 threads --------
DEV void breduce2(float& a, float& b, float* red, int tid) {
#pragma unroll
  for (int off = 32; off > 0; off >>= 1) {
    a += __shfl_down(a, off);
    b += __shfl_down(b, off);
  }
  int lane = tid & 63, wv = tid >> 6;
  if (lane == 0) { red[wv * 2] = a; red[wv * 2 + 1] = b; }
  __syncthreads();
  a = red[0] + red[2] + red[4] + red[6];
  b = red[1] + red[3] + red[5] + red[7];
}

// -------- GroupNorm stats (+ optional bf16 copy of x) --------
template <int XB>
__global__ void k_gn_partial(const float* __restrict__ x, float* __restrict__ partials,
                             u16* __restrict__ xb) {
  __shared__ float red[8];
  int chunk = blockIdx.x;
  size_t base4 = ((size_t)chunk) << 12;
  const float4* x4 = (const float4*)x;
  float a = 0.f, b = 0.f;
#pragma unroll 4
  for (int i = 0; i < 16; ++i) {
    size_t idx = base4 + (i << 8) + threadIdx.x;
    float4 v = x4[idx];
    a += v.x + v.y + v.z + v.w;
    b += v.x * v.x + v.y * v.y + v.z * v.z + v.w * v.w;
    if (XB) {
      u16 t[4] = {f2b(v.x), f2b(v.y), f2b(v.z), f2b(v.w)};
      *(uint2*)(xb + (idx << 2)) = *(uint2*)t;
    }
  }
  breduce2(a, b, red, threadIdx.x);
  if (threadIdx.x == 0) { partials[chunk * 2] = a; partials[chunk * 2 + 1] = b; }
}

__global__ void k_gn_final(const float* __restrict__ partials, float* __restrict__ stats) {
  int g = blockIdx.x, lane = threadIdx.x;
  float a = partials[(((g << 6) + lane) << 1)];
  float b = partials[(((g << 6) + lane) << 1) + 1];
#pragma unroll
  for (int off = 32; off > 0; off >>= 1) {
    a += __shfl_down(a, off);
    b += __shfl_down(b, off);
  }
  if (lane == 0) {
    float mean = a * (1.f / 1048576.f);
    float var = b * (1.f / 1048576.f) - mean * mean;
    stats[g << 1] = mean;
    stats[(g << 1) + 1] = rsqrtf(var + 1e-5f);
  }
}

// -------- style linear --------
__global__ void k_style(const float* __restrict__ sc, const float* __restrict__ gw,
                        const float* __restrict__ gb, const float* __restrict__ sw,
                        const float* __restrict__ sb, float* __restrict__ gp,
                        float* __restrict__ stok) {
  __shared__ float row[512];
  int b = blockIdx.y, part = blockIdx.x, tid = threadIdx.x;
  row[tid] = sc[(b << 9) + tid];
  row[tid + 256] = sc[(b << 9) + tid + 256];
  __syncthreads();
  if (part < 2) {
    int o = (part << 8) + tid;
    float s = gb[o];
    const float* wr = gw + ((size_t)o << 9);
#pragma unroll 8
    for (int j = 0; j < 512; ++j) s += row[j] * wr[j];
    gp[(b << 9) + o] = s;
  } else {
    float s = sb[tid];
    const float* wr = sw + ((size_t)tid << 9);
#pragma unroll 8
    for (int j = 0; j < 512; ++j) s += row[j] * wr[j];
    stok[(b << 8) + tid] = s;
  }
}

// -------- style tokens + LN --------
__global__ void k_styk(const float* __restrict__ tb, const float* __restrict__ stok,
                       const float* __restrict__ g, const float* __restrict__ bt,
                       float* __restrict__ styk) {
  __shared__ float red[8];
  int r = blockIdx.x;
  int b = r >> 6, t = r & 63;
  int c = threadIdx.x;
  float v = tb[(t << 8) + c] + stok[(b << 8) + c];
  float a = v, bb = v * v;
  breduce2(a, bb, red, c);
  float mean = a * (1.f / 256.f);
  float var = bb * (1.f / 256.f) - mean * mean;
  float rs = rsqrtf(var + 1e-5f);
  styk[((size_t)r << 8) + c] = (v - mean) * rs * g[c] + bt[c];
}

// -------- K/V projections of style tokens -> bf16 --------
__global__ void k_kv(const float* __restrict__ styk, const float* __restrict__ kw,
                     const float* __restrict__ kb, const float* __restrict__ vw,
                     const float* __restrict__ vb, u16* __restrict__ kmat,
                     u16* __restrict__ vmat) {
  __shared__ float srow[256];
  int r = blockIdx.x, c = threadIdx.x;
  srow[c] = styk[((size_t)r << 8) + c];
  __syncthreads();
  float sk = kb[c], sv = vb[c];
  const float* kr = kw + ((size_t)c << 8);
  const float* vr = vw + ((size_t)c << 8);
#pragma unroll 8
  for (int j = 0; j < 256; ++j) { sk += srow[j] * kr[j]; sv += srow[j] * vr[j]; }
  kmat[((size_t)r << 8) + c] = f2b(sk);
  vmat[((size_t)r << 8) + c] = f2b(sv);
}

// -------- pos hidden --------
__global__ void k_posh(const float* __restrict__ w1, const float* __restrict__ b1,
                       u16* __restrict__ posh) {
  int i = blockIdx.x * 256 + threadIdx.x;
  int stride = gridDim.x * 256;
  for (; i < 16384 * 256; i += stride) {
    int p = i >> 8, c = i & 255;
    int y = p >> 7, x = p & 127;
    float gx = -1.f + 2.f * (float)x / 127.f;
    float gy = -1.f + 2.f * (float)y / 127.f;
    float v = gx * w1[c << 1] + gy * w1[(c << 1) + 1] + b1[c];
    posh[i] = f2b(silu_f(v));
  }
}

// ======== MFMA bf16 GEMM (NT), m97 structure + XCD-grouped swizzle ========
template <int ACT, int BIAS, int RES, int SPLIT>
__global__ __launch_bounds__(256, 2) void k_gemm2(
    const u16* __restrict__ A, const u16* __restrict__ Bw,
    const float* __restrict__ bias, const u16* __restrict__ res,
    u16* __restrict__ o0, u16* __restrict__ o1, u16* __restrict__ o2,
    int M, int N, int K) {
  __shared__ __align__(16) u16 lds[17408];
  u16* sA = lds;
  u16* sB = lds + 4096;
  const int tid = threadIdx.x;
  const int lane = tid & 63, wv = tid >> 6;
  // XCD-grouped swizzle: same-A blocks -> same XCD, adjacent in time.
  const int nx = gridDim.x;
  const int L = blockIdx.x + nx * blockIdx.y;
  const int xcd = L & 7;
  const int t = L >> 3;
  const int nblk = t % nx;
  const int mblk = ((t / nx) << 3) + xcd;
  const int m0 = mblk << 7, n0 = nblk << 7;
  const int l15 = lane & 15, lg = lane >> 4;
  const int wr = wv >> 1, wc = wv & 1;

  const int gofs = (((lane & 3) ^ ((lane >> 3) & 3)) << 3);
  const int lrow = lane >> 2;
  const u16* Ag0 = A + (size_t)(m0 + (wv << 5) + lrow) * K + gofs;
  const u16* Ag1 = A + (size_t)(m0 + (wv << 5) + 16 + lrow) * K + gofs;
  const u16* Bg0 = Bw + (size_t)(n0 + (wv << 5) + lrow) * K + gofs;
  const u16* Bg1 = Bw + (size_t)(n0 + (wv << 5) + 16 + lrow) * K + gofs;
  u16* lA0 = sA + (wv << 10);
  u16* lA1 = sA + (wv << 10) + 512;
  u16* lB0 = sB + (wv << 10);
  u16* lB1 = sB + (wv << 10) + 512;

  const int roff = l15 * 32 + (((lg ^ ((l15 >> 1) & 3))) << 3);
  const int abase = (wr << 6) * 32;
  const int bbase = (wc << 6) * 32;

  f32x4 acc[4][4];
  f32x4 zz = {0.f, 0.f, 0.f, 0.f};
#pragma unroll
  for (int mi = 0; mi < 4; ++mi)
#pragma unroll
    for (int ni = 0; ni < 4; ++ni) acc[mi][ni] = zz;

  for (int kt = 0; kt < K; kt += 32) {
    __syncthreads();
    gload16(Ag0 + kt, lA0);
    gload16(Ag1 + kt, lA1);
    gload16(Bg0 + kt, lB0);
    gload16(Bg1 + kt, lB1);
    __syncthreads();
    bf16x8 af[4], bfv[4];
#pragma unroll
    for (int mi = 0; mi < 4; ++mi) af[mi] = *(const bf16x8*)&sA[abase + mi * 512 + roff];
#pragma unroll
    for (int ni = 0; ni < 4; ++ni) bfv[ni] = *(const bf16x8*)&sB[bbase + ni * 512 + roff];
#pragma unroll
    for (int mi = 0; mi < 4; ++mi)
#pragma unroll
      for (int ni = 0; ni < 4; ++ni)
        acc[mi][ni] = __builtin_amdgcn_mfma_f32_16x16x32_bf16(af[mi], bfv[ni], acc[mi][ni], 0, 0, 0);
  }

  float bv[4];
#pragma unroll
  for (int ni = 0; ni < 4; ++ni)
    bv[ni] = BIAS ? bias[n0 + (wc << 6) + (ni << 4) + l15] : 0.0f;
  __syncthreads();
  const int lg4 = lg << 2;
#pragma unroll
  for (int mi = 0; mi < 4; ++mi) {
#pragma unroll
    for (int ni = 0; ni < 4; ++ni) {
#pragma unroll
      for (int r = 0; r < 4; ++r) {
        int row = (wr << 6) + (mi << 4) + lg4 + r;
        int col = (wc << 6) + (ni << 4) + l15;
        float v = acc[mi][ni][r] + bv[ni];
        if (ACT == 1) v = silu_f(v);
        lds[row * 136 + col] = f2b(v);
      }
    }
  }
  __syncthreads();
  u16* obase;
  int cb, ldc;
  if (SPLIT) {
    int sel = n0 >> 8;
    obase = sel == 0 ? o0 : (sel == 1 ? o1 : o2);
    cb = n0 & 255;
    ldc = 256;
  } else {
    obase = o0;
    cb = n0;
    ldc = N;
  }
#pragma unroll
  for (int i = 0; i < 8; ++i) {
    int flat = (i << 8) + tid;
    int row = flat >> 4, c8 = (flat & 15) << 3;
    uint4 vv = *(const uint4*)&lds[row * 136 + c8];
    size_t oi = (size_t)(m0 + row) * ldc + cb + c8;
    if (RES) {
      uint4 rr = *(const uint4*)(res + oi);
      float a8[8], r8[8];
      up8(vv, a8);
      up8(rr, r8);
      u16 t8[8];
#pragma unroll
      for (int e = 0; e < 8; ++e) t8[e] = f2b(a8[e] + r8[e]);
      vv = *(const uint4*)t8;
    }
    *(uint4*)(obase + oi) = vv;
  }
}

// -------- fused: GN-normalize + transpose + pos_emb + qn LayerNorm -> tokq --------
template <int XB>
__global__ __launch_bounds__(256) void k_tokpe2(
    const float* __restrict__ x, const u16* __restrict__ xb,
    const float* __restrict__ stats, const u16* __restrict__ pe,
    const float* __restrict__ qg, const float* __restrict__ qb2,
    u16* __restrict__ tokq) {
  __shared__ u16 T[256 * 72];
  __shared__ float red[64][8];
  const int tid = threadIdx.x;
  const int p0 = blockIdx.x << 6, b = blockIdx.y;
  {
    const int c = tid;
    const int g = (b << 2) + (c >> 6);
    const float mu = stats[g << 1], rs = stats[(g << 1) + 1];
    const size_t base = (((size_t)(b << 8) + c) << 14) + p0;
#pragma unroll
    for (int j8 = 0; j8 < 8; ++j8) {
      float f[8];
      if (XB) {
        up8(*(const uint4*)(xb + base + (j8 << 3)), f);
      } else {
        float4 v0 = *(const float4*)(x + base + (j8 << 3));
        float4 v1 = *(const float4*)(x + base + (j8 << 3) + 4);
        f[0] = v0.x; f[1] = v0.y; f[2] = v0.z; f[3] = v0.w;
        f[4] = v1.x; f[5] = v1.y; f[6] = v1.z; f[7] = v1.w;
      }
      u16 t8[8];
#pragma unroll
      for (int e = 0; e < 8; ++e) t8[e] = f2b((f[e] - mu) * rs);
      *(uint4*)&T[c * 72 + (j8 << 3)] = *(uint4*)t8;
    }
  }
  __syncthreads();
  const int p = tid & 63, cq = tid >> 6;
  const size_t pebase = (((size_t)(p0 + p)) << 8) + (cq << 6);
  float vbuf[64];
  float a = 0.f, s = 0.f;
#pragma unroll
  for (int q = 0; q < 8; ++q) {
    float pf[8];
    up8(*(const uint4*)(pe + pebase + (q << 3)), pf);
#pragma unroll
    for (int e = 0; e < 8; ++e) {
      int j = (q << 3) + e;
      float v = b2f(T[((cq << 6) + j) * 72 + p]) + pf[e];
      vbuf[j] = v;
      a += v; s += v * v;
    }
  }
  red[p][cq << 1] = a;
  red[p][(cq << 1) + 1] = s;
  __syncthreads();
  float sa = red[p][0] + red[p][2] + red[p][4] + red[p][6];
  float ss = red[p][1] + red[p][3] + red[p][5] + red[p][7];
  float mean = sa * (1.f / 256.f);
  float var = ss * (1.f / 256.f) - mean * mean;
  float rsg = rsqrtf(var + 1e-5f);
  const size_t orow = (((size_t)(b << 14) + p0 + p) << 8) + (cq << 6);
#pragma unroll
  for (int q = 0; q < 8; ++q) {
    u16 t8[8];
#pragma unroll
    for (int e = 0; e < 8; ++e) {
      int j = (q << 3) + e;
      t8[e] = f2b((vbuf[j] - mean) * rsg * qg[(cq << 6) + j] + qb2[(cq << 6) + j]);
    }
    *(uint4*)(tokq + orow + (q << 3)) = *(uint4*)t8;
  }
}

// -------- vectorized row LayerNorm (256) --------
__global__ __launch_bounds__(256) void k_rowln8(const u16* __restrict__ in,
                                                const float* __restrict__ g,
                                                const float* __restrict__ bt,
                                                u16* __restrict__ out) {
  __shared__ float gs[256], bs[256];
  int tid = threadIdx.x;
  gs[tid] = g[tid];
  bs[tid] = bt[tid];
  __syncthreads();
  size_t base = (((size_t)(blockIdx.x << 5) + (tid >> 3)) << 8) + ((tid & 7) << 5);
  float v[32];
#pragma unroll
  for (int q = 0; q < 4; ++q) up8(*(const uint4*)(in + base + (q << 3)), &v[q << 3]);
  float a = 0.f, b = 0.f;
#pragma unroll
  for (int j = 0; j < 32; ++j) { a += v[j]; b += v[j] * v[j]; }
#pragma unroll
  for (int m = 1; m <= 4; m <<= 1) { a += __shfl_xor(a, m); b += __shfl_xor(b, m); }
  float mean = a * (1.f / 256.f);
  float var = b * (1.f / 256.f) - mean * mean;
  float rs = rsqrtf(var + 1e-5f);
  int c0 = (tid & 7) << 5;
#pragma unroll
  for (int q = 0; q < 4; ++q) {
    u16 tmp[8];
#pragma unroll
    for (int e = 0; e < 8; ++e) {
      int j = (q << 3) + e;
      tmp[e] = f2b((v[j] - mean) * rs * gs[c0 + j] + bs[c0 + j]);
    }
    *(uint4*)(out + base + (q << 3)) = *(uint4*)tmp;
  }
}

// -------- MFMA cross attention (round-6 barriered version) --------
__global__ __launch_bounds__(256, 2) void k_cross_mfma(
    const u16* __restrict__ qmat, const u16* __restrict__ kmat,
    const u16* __restrict__ vmat, u16* __restrict__ attn_out) {
  __shared__ u16 Kl[64 * 72];
  __shared__ u16 Vt[64 * 72];
  __shared__ u16 Pl[4][64 * 72];
  const int tid = threadIdx.x;
  const int lane = tid & 63, wv = tid >> 6;
  const int l15 = lane & 15, lg = lane >> 4;
  const int b = blockIdx.z, h = blockIdx.y;
  const int q0 = blockIdx.x << 8;
  for (int c = tid; c < 512; c += 256) {
    int t = c >> 3, dg = (c & 7) << 3;
    size_t src = (((size_t)(b << 6) + t) << 8) + (h << 6) + dg;
    *(uint4*)&Kl[t * 72 + dg] = *(const uint4*)(kmat + src);
    uint4 vv = *(const uint4*)(vmat + src);
    const u16* pv = (const u16*)&vv;
#pragma unroll
    for (int e = 0; e < 8; ++e) Vt[(dg + e) * 72 + t] = pv[e];
  }
  __syncthreads();
  const size_t qrow0 = (size_t)(b << 14) + q0 + (wv << 6);
  f32x4 acc[4][4];
  f32x4 zz = {0.f, 0.f, 0.f, 0.f};
#pragma unroll
  for (int mi = 0; mi < 4; ++mi)
#pragma unroll
    for (int ni = 0; ni < 4; ++ni) acc[mi][ni] = zz;
#pragma unroll
  for (int ks = 0; ks < 2; ++ks) {
    bf16x8 a[4], bbf[4];
#pragma unroll
    for (int mi = 0; mi < 4; ++mi)
      a[mi] = *(const bf16x8*)(qmat + ((qrow0 + (mi << 4) + l15) << 8) + (h << 6) +
                               (ks << 5) + (lg << 3));
#pragma unroll
    for (int ni = 0; ni < 4; ++ni)
      bbf[ni] = *(const bf16x8*)&Kl[((ni << 4) + l15) * 72 + (ks << 5) + (lg << 3)];
#pragma unroll
    for (int mi = 0; mi < 4; ++mi)
#pragma unroll
      for (int ni = 0; ni < 4; ++ni)
        acc[mi][ni] = __builtin_amdgcn_mfma_f32_16x16x32_bf16(a[mi], bbf[ni], acc[mi][ni], 0, 0, 0);
  }
  const float SC = 0.25f;
#pragma unroll
  for (int mi = 0; mi < 4; ++mi) {
#pragma unroll
    for (int r = 0; r < 4; ++r) {
      float rm = acc[mi][0][r];
#pragma unroll
      for (int ni = 1; ni < 4; ++ni) rm = fmaxf(rm, acc[mi][ni][r]);
      rm = redmax16(rm);
      float pv[4];
      float rs = 0.f;
#pragma unroll
      for (int ni = 0; ni < 4; ++ni) {
        pv[ni] = __expf((acc[mi][ni][r] - rm) * SC);
        rs += pv[ni];
      }
      rs = redsum16(rs);
      float inv = 1.f / rs;
      int row = (mi << 4) + (lg << 2) + r;
#pragma unroll
      for (int ni = 0; ni < 4; ++ni)
        Pl[wv][row * 72 + (ni << 4) + l15] = f2b(pv[ni] * inv);
    }
  }
  __syncthreads();
  f32x4 o[4][4];
#pragma unroll
  for (int mi = 0; mi < 4; ++mi)
#pragma unroll
    for (int ni = 0; ni < 4; ++ni) o[mi][ni] = zz;
#pragma unroll
  for (int ks = 0; ks < 2; ++ks) {
    bf16x8 a[4], bbf[4];
#pragma unroll
    for (int mi = 0; mi < 4; ++mi)
      a[mi] = *(const bf16x8*)&Pl[wv][((mi << 4) + l15) * 72 + (ks << 5) + (lg << 3)];
#pragma unroll
    for (int ni = 0; ni < 4; ++ni)
      bbf[ni] = *(const bf16x8*)&Vt[((ni << 4) + l15) * 72 + (ks << 5) + (lg << 3)];
#pragma unroll
    for (int mi = 0; mi < 4; ++mi)
#pragma unroll
      for (int ni = 0; ni < 4; ++ni)
        o[mi][ni] = __builtin_amdgcn_mfma_f32_16x16x32_bf16(a[mi], bbf[ni], o[mi][ni], 0, 0, 0);
  }
  __syncthreads();
#pragma unroll
  for (int mi = 0; mi < 4; ++mi)
#pragma unroll
    for (int ni = 0; ni < 4; ++ni)
#pragma unroll
      for (int r = 0; r < 4; ++r)
        Pl[wv][((mi << 4) + (lg << 2) + r) * 72 + (ni << 4) + l15] = f2b(o[mi][ni][r]);
  __syncthreads();
  const int l8r = lane >> 3, l8c = lane & 7;
#pragma unroll
  for (int it = 0; it < 8; ++it) {
    int row = (it << 3) + l8r;
    uint4 vv = *(const uint4*)&Pl[wv][row * 72 + (l8c << 3)];
    *(uint4*)(attn_out + ((qrow0 + row) << 8) + (h << 6) + (l8c << 3)) = vv;
  }
}

// -------- MFMA window attention v3: 4 blocks/CU via two-pass P [64][40] --------
__global__ __launch_bounds__(256, 4) void k_win_mfma(
    const u16* __restrict__ qb, const u16* __restrict__ kbuf,
    const u16* __restrict__ vbuf, u16* __restrict__ wout) {
  __shared__ u16 Vt[4][32 * 72];   // per-wave V^T [d 0..31][t 0..63 pad 72]
  __shared__ u16 Pl[4][64 * 40];   // per-wave P half-tile / O staging
  const int tid = threadIdx.x;
  const int lane = tid & 63, wv = tid >> 6;
  const int l15 = lane & 15, lg = lane >> 4;
  const int win = blockIdx.x, b = blockIdx.y;
  const int wbase = ((win >> 4) << 10) + ((win & 15) << 3);
  const size_t bbase = (size_t)b << 14;
  const float SC = 0.17677669529663687f;
  f32x4 zz = {0.f, 0.f, 0.f, 0.f};
#pragma unroll 1
  for (int h2 = 0; h2 < 2; ++h2) {
    const int h = (wv << 1) + h2;
    const int co = h << 5;
    __syncthreads();  // loose phase alignment (all LDS is wave-private)
    // stage V^T (wave-private)
    {
      int p = wbase + ((lane >> 3) << 7) + (lane & 7);
      const u16* src = vbuf + ((bbase + p) << 8) + co;
#pragma unroll
      for (int c = 0; c < 4; ++c) {
        uint4 vv = *(const uint4*)(src + (c << 3));
        const u16* pe = (const u16*)&vv;
#pragma unroll
        for (int e = 0; e < 8; ++e) Vt[wv][((c << 3) + e) * 72 + lane] = pe[e];
      }
    }
    // S = Q K^T  (M=64, N=64, K=32)
    f32x4 acc[4][4];
#pragma unroll
    for (int mi = 0; mi < 4; ++mi)
#pragma unroll
      for (int ni = 0; ni < 4; ++ni) acc[mi][ni] = zz;
    {
      bf16x8 a[4], bbf[4];
#pragma unroll
      for (int mi = 0; mi < 4; ++mi) {
        int t = (mi << 4) + l15;
        int p = wbase + ((t >> 3) << 7) + (t & 7);
        a[mi] = *(const bf16x8*)(qb + ((bbase + p) << 8) + co + (lg << 3));
      }
#pragma unroll
      for (int ni = 0; ni < 4; ++ni) {
        int t = (ni << 4) + l15;
        int p = wbase + ((t >> 3) << 7) + (t & 7);
        bbf[ni] = *(const bf16x8*)(kbuf + ((bbase + p) << 8) + co + (lg << 3));
      }
#pragma unroll
      for (int mi = 0; mi < 4; ++mi)
#pragma unroll
        for (int ni = 0; ni < 4; ++ni)
          acc[mi][ni] = __builtin_amdgcn_mfma_f32_16x16x32_bf16(a[mi], bbf[ni], acc[mi][ni], 0, 0, 0);
    }
    // softmax over kv cols (in-lane ni + cross-lane l15); normalized P in acc
#pragma unroll
    for (int mi = 0; mi < 4; ++mi) {
#pragma unroll
      for (int r = 0; r < 4; ++r) {
        float rm = acc[mi][0][r];
#pragma unroll
        for (int ni = 1; ni < 4; ++ni) rm = fmaxf(rm, acc[mi][ni][r]);
        rm = redmax16(rm);
        float pv[4];
        float rs = 0.f;
#pragma unroll
        for (int ni = 0; ni < 4; ++ni) {
          pv[ni] = __expf((acc[mi][ni][r] - rm) * SC);
          rs += pv[ni];
        }
        rs = redsum16(rs);
        float inv = 1.f / rs;
#pragma unroll
        for (int ni = 0; ni < 4; ++ni) acc[mi][ni][r] = pv[ni] * inv;
      }
    }
    // O = P V via two passes through the [64][40] wave-private buffer.
    f32x4 o[4][2];
#pragma unroll
    for (int mi = 0; mi < 4; ++mi)
#pragma unroll
      for (int ni = 0; ni < 2; ++ni) o[mi][ni] = zz;
#pragma unroll 1
    for (int ks = 0; ks < 2; ++ks) {
      // write P cols [ks*32, ks*32+32) into Pl[wv][row][0..31]
#pragma unroll
      for (int mi = 0; mi < 4; ++mi)
#pragma unroll
        for (int r = 0; r < 4; ++r) {
          int row = (mi << 4) + (lg << 2) + r;
#pragma unroll
          for (int n2 = 0; n2 < 2; ++n2)
            Pl[wv][row * 40 + (n2 << 4) + l15] = f2b(acc[mi][(ks << 1) + n2][r]);
        }
      // same-wave in-order DS pipe: reads below see the writes above
      bf16x8 a[4], bbf[2];
#pragma unroll
      for (int mi = 0; mi < 4; ++mi)
        a[mi] = *(const bf16x8*)&Pl[wv][((mi << 4) + l15) * 40 + (lg << 3)];
#pragma unroll
      for (int ni = 0; ni < 2; ++ni)
        bbf[ni] = *(const bf16x8*)&Vt[wv][((ni << 4) + l15) * 72 + (ks << 5) + (lg << 3)];
#pragma unroll
      for (int mi = 0; mi < 4; ++mi)
#pragma unroll
        for (int ni = 0; ni < 2; ++ni)
          o[mi][ni] = __builtin_amdgcn_mfma_f32_16x16x32_bf16(a[mi], bbf[ni], o[mi][ni], 0, 0, 0);
    }
    // stage O (64x32) into Pl[wv][row][0..31], coalesced 16B writes out
#pragma unroll
    for (int mi = 0; mi < 4; ++mi)
#pragma unroll
      for (int ni = 0; ni < 2; ++ni)
#pragma unroll
        for (int r = 0; r < 4; ++r)
          Pl[wv][((mi << 4) + (lg << 2) + r) * 40 + (ni << 4) + l15] = f2b(o[mi][ni][r]);
#pragma unroll
    for (int it = 0; it < 4; ++it) {
      int row = (it << 4) + (lane >> 2);
      int cg = (lane & 3) << 3;
      uint4 vv = *(const uint4*)&Pl[wv][row * 40 + cg];
      int p = wbase + ((row >> 3) << 7) + (row & 7);
      *(uint4*)(wout + ((bbase + p) << 8) + co + cg) = vv;
    }
  }
}

// -------- xrt = roll(h,(-4,-4)) NHWC bf16 --------
template <int XB>
__global__ void k_xrt(const float* __restrict__ x, const u16* __restrict__ xb,
                      const u16* __restrict__ sc2, const float* __restrict__ stats,
                      const float* __restrict__ gp, const float* __restrict__ gamma,
                      u16* __restrict__ xrt) {
  __shared__ float A[64][33];
  __shared__ float Bt[32][65];
  int p0 = blockIdx.x << 6, c0 = blockIdx.y << 5, b = blockIdx.z;
  int tid = threadIdx.x;
#pragma unroll
  for (int i = 0; i < 8; ++i) {
    int flat = (i << 8) + tid;
    int pi = flat >> 5, ci = flat & 31;
    A[pi][ci] = b2f(sc2[(((size_t)(b << 14) + p0 + pi) << 8) + c0 + ci]);
  }
  __syncthreads();
#pragma unroll
  for (int i = 0; i < 8; ++i) {
    int flat = (i << 8) + tid;
    int cc = flat >> 6, px = flat & 63;
    int cch = c0 + cc;
    int g = (b << 2) + (cch >> 6);
    float mu = stats[g << 1], rs = stats[(g << 1) + 1];
    size_t xi = (((size_t)(b << 8) + cch) << 14) + p0 + px;
    float xv = XB ? b2f(xb[xi]) : x[xi];
    float val = xv + (xv - mu) * rs * gp[(b << 9) + cch] + gp[(b << 9) + 256 + cch] +
                A[px][cc] * gamma[cch];
    Bt[cc][px] = val;
  }
  __syncthreads();
#pragma unroll
  for (int i = 0; i < 8; ++i) {
    int flat = (i << 8) + tid;
    int xi2 = flat >> 5, ci = flat & 31;
    int p = p0 + xi2;
    int yy = p >> 7, xx = p & 127;
    int pr = (((yy + 124) & 127) << 7) + ((xx + 124) & 127);
    xrt[(((size_t)(b << 14) + pr) << 8) + c0 + ci] = f2b(Bt[ci][xi2]);
  }
}

// -------- final: dout = h (from xr) + rollback(out2); both NHWC rolled --------
__global__ void k_final2(const u16* __restrict__ xr, const u16* __restrict__ out2,
                         float* __restrict__ dout) {
  __shared__ float L[64][33];
  int bx = blockIdx.x;
  int y = bx >> 1, x0 = (bx & 1) << 6;
  int c0 = blockIdx.y << 5, b = blockIdx.z;
  int tid = threadIdx.x;
#pragma unroll
  for (int i = 0; i < 8; ++i) {
    int flat = (i << 8) + tid;
    int xi = flat >> 5, ci = flat & 31;
    int xx = x0 + xi;
    int pr = (((y + 124) & 127) << 7) + ((xx + 124) & 127);
    size_t ii = (((size_t)(b << 14) + pr) << 8) + c0 + ci;
    L[xi][ci] = b2f(xr[ii]) + b2f(out2[ii]);
  }
  __syncthreads();
#pragma unroll
  for (int i = 0; i < 8; ++i) {
    int flat = (i << 8) + tid;
    int cc = flat >> 6, xi2 = flat & 63;
    size_t idx = (((size_t)(b << 8) + c0 + cc) << 14) + (y << 7) + x0 + xi2;
    dout[idx] = L[xi2][cc];
  }
}

extern "C" void kernel_launch(void* const* d_in, const int* in_sizes, int n_in,
                              void* d_out, int out_size, void* d_ws, size_t ws_size,
                              hipStream_t stream) {
  (void)in_sizes; (void)n_in; (void)out_size;
  const float* x = (const float*)d_in[0];
  const float* style = (const float*)d_in[1];
  const float* qkv_w = (const float*)d_in[2];
  const float* spat_w = (const float*)d_in[3];
  const float* gproj_w = (const float*)d_in[4];
  const float* gproj_b = (const float*)d_in[5];
  const float* tokens_basis = (const float*)d_in[6];
  const float* sproj_w = (const float*)d_in[7];
  const float* sproj_b = (const float*)d_in[8];
  const float* pos_w1 = (const float*)d_in[9];
  const float* pos_b1 = (const float*)d_in[10];
  const float* pos_w2 = (const float*)d_in[11];
  const float* pos_b2 = (const float*)d_in[12];
  const float* q_w = (const float*)d_in[13];
  const float* q_b = (const float*)d_in[14];
  const float* k_w = (const float*)d_in[15];
  const float* k_b = (const float*)d_in[16];
  const float* v_w = (const float*)d_in[17];
  const float* v_b = (const float*)d_in[18];
  const float* o_w = (const float*)d_in[19];
  const float* o_b = (const float*)d_in[20];
  const float* ffn_w1 = (const float*)d_in[21];
  const float* ffn_b1 = (const float*)d_in[22];
  const float* ffn_w2 = (const float*)d_in[23];
  const float* ffn_b2 = (const float*)d_in[24];
  const float* tn_g = (const float*)d_in[25];
  const float* tn_b = (const float*)d_in[26];
  const float* qn_g = (const float*)d_in[27];
  const float* qn_b = (const float*)d_in[28];
  const float* fn_g = (const float*)d_in[29];
  const float* fn_b = (const float*)d_in[30];
  const float* gamma = (const float*)d_in[31];
  float* dout = (float*)d_out;

  char* w = (char*)d_ws;
  size_t off = 0;
  auto alloc = [&](size_t sz) {
    char* p = w + off;
    off += (sz + 255) & ~(size_t)255;
    return (void*)p;
  };
  float* partials = (float*)alloc(1024 * 2 * 4);
  float* stats = (float*)alloc(32 * 4);
  float* gp = (float*)alloc(4 * 512 * 4);
  float* stok = (float*)alloc(4 * 256 * 4);
  float* styk = (float*)alloc(4 * 64 * 256 * 4);
  u16* kmat = (u16*)alloc(4 * 64 * 256 * 2);
  u16* vmat = (u16*)alloc(4 * 64 * 256 * 2);
  u16* wb_q = (u16*)alloc(65536 * 2);
  u16* wb_o = (u16*)alloc(65536 * 2);
  u16* wb_w1 = (u16*)alloc(131072 * 2);
  u16* wb_w2 = (u16*)alloc(131072 * 2);
  u16* wb_qkv = (u16*)alloc(196608 * 2);
  u16* wb_sp = (u16*)alloc(65536 * 2);
  u16* wb_p2 = (u16*)alloc(65536 * 2);
  const size_t SLOT = (size_t)65536 * 256 * 2;  // 32 MiB
  u16* S0 = (u16*)alloc(SLOT);
  u16* S1 = (u16*)alloc(SLOT);
  u16* S2 = (u16*)alloc(SLOT);
  size_t off_base = off;
  u16* xb = (u16*)alloc((size_t)16777216 * 2);  // 32 MiB bf16 copy of x
  if (ws_size < off_base) return;
  const int XB = (ws_size >= off) ? 1 : 0;

  // d_out is exactly 64 MiB: ffn_h uses all of it; kwin/vwin split it.
  u16* ffn_h = (u16*)d_out;                            // [0, 64 MiB)
  u16* kwin = (u16*)d_out;                             // [0, 32 MiB)
  u16* vwin = (u16*)d_out + (size_t)65536 * 256;       // [32, 64 MiB)

  WConv wc = {q_w, o_w, ffn_w1, ffn_w2, qkv_w, spat_w, pos_w2,
              wb_q, wb_o, wb_w1, wb_w2, wb_qkv, wb_sp, wb_p2};
  k_conv_all<<<704, 256, 0, stream>>>(wc);

  if (XB) k_gn_partial<1><<<1024, 256, 0, stream>>>(x, partials, xb);
  else k_gn_partial<0><<<1024, 256, 0, stream>>>(x, partials, xb);
  k_gn_final<<<16, 64, 0, stream>>>(partials, stats);

  k_style<<<dim3(3, 4), 256, 0, stream>>>(style, gproj_w, gproj_b, sproj_w, sproj_b, gp, stok);
  k_styk<<<256, 256, 0, stream>>>(tokens_basis, stok, tn_g, tn_b, styk);
  k_kv<<<256, 256, 0, stream>>>(styk, k_w, k_b, v_w, v_b, kmat, vmat);

  k_posh<<<4096, 256, 0, stream>>>(pos_w1, pos_b1, S0);
  k_gemm2<0, 1, 0, 0><<<dim3(2, 128), 256, 0, stream>>>(S0, wb_p2, pos_b2, nullptr,
                                                        S1, nullptr, nullptr, 16384, 256, 256);

  // fused GN-transpose + pos_emb + qn LN -> tokq (S2)
  if (XB) k_tokpe2<1><<<dim3(256, 4), 256, 0, stream>>>(x, xb, stats, S1, qn_g, qn_b, S2);
  else k_tokpe2<0><<<dim3(256, 4), 256, 0, stream>>>(x, xb, stats, S1, qn_g, qn_b, S2);

  k_gemm2<0, 1, 0, 0><<<dim3(2, 512), 256, 0, stream>>>(S2, wb_q, q_b, nullptr,
                                                        S1, nullptr, nullptr, 65536, 256, 256);
  k_cross_mfma<<<dim3(64, 4, 4), 256, 0, stream>>>(S1, kmat, vmat, S0);
  k_gemm2<0, 1, 0, 0><<<dim3(2, 512), 256, 0, stream>>>(S0, wb_o, o_b, nullptr,
                                                        S2, nullptr, nullptr, 65536, 256, 256);

  k_rowln8<<<2048, 256, 0, stream>>>(S2, fn_g, fn_b, S1);
  k_gemm2<1, 1, 0, 0><<<dim3(4, 512), 256, 0, stream>>>(S1, wb_w1, ffn_b1, nullptr,
                                                        ffn_h, nullptr, nullptr, 65536, 512, 256);
  k_gemm2<0, 1, 1, 0><<<dim3(2, 512), 256, 0, stream>>>(ffn_h, wb_w2, ffn_b2, S2,
                                                        S0, nullptr, nullptr, 65536, 256, 512);

  if (XB) k_xrt<1><<<dim3(256, 8, 4), 256, 0, stream>>>(x, xb, S0, stats, gp, gamma, S1);
  else k_xrt<0><<<dim3(256, 8, 4), 256, 0, stream>>>(x, xb, S0, stats, gp, gamma, S1);

  // qkv: q->S2, k->kwin (d_out lo), v->vwin (d_out hi). S0 (sc2) now dead.
  k_gemm2<0, 0, 0, 1><<<dim3(6, 512), 256, 0, stream>>>(S1, wb_qkv, nullptr, nullptr,
                                                        S2, kwin, vwin, 65536, 768, 256);

  // window attention -> S0 (dead sc2 slot); spat proj S0 -> S2
  k_win_mfma<<<dim3(256, 4), 256, 0, stream>>>(S2, kwin, vwin, S0);
  k_gemm2<0, 0, 0, 0><<<dim3(2, 512), 256, 0, stream>>>(S0, wb_sp, nullptr, nullptr,
                                                        S2, nullptr, nullptr, 65536, 256, 256);

  // final: h lives in xr (S1, rolled NHWC); out2 in S2 (rolled NHWC)
  k_final2<<<dim3(256, 8, 4), 256, 0, stream>>>(S1, S2, dout);
}

// Round 9
// 410.469 us; speedup vs baseline: 1.1520x; 1.1520x over previous
//
#include <hip/hip_runtime.h>
#include <stdint.h>

#define DEV __device__ __forceinline__

typedef unsigned short u16;
typedef unsigned int u32;
typedef __attribute__((ext_vector_type(8))) __bf16 bf16x8;
typedef __attribute__((ext_vector_type(4))) float f32x4;

DEV u16 f2b(float f) {
  u32 u = __float_as_uint(f);
  u32 r = (u + 0x7FFFu + ((u >> 16) & 1u)) >> 16;
  return (u16)r;
}
DEV float b2f(u16 u) { return __uint_as_float(((u32)u) << 16); }
DEV void up2(u32 u, float& a, float& b) {
  a = __uint_as_float(u << 16);
  b = __uint_as_float(u & 0xffff0000u);
}
DEV void up8(uint4 t, float* d) {
  up2(t.x, d[0], d[1]); up2(t.y, d[2], d[3]);
  up2(t.z, d[4], d[5]); up2(t.w, d[6], d[7]);
}
DEV float silu_f(float v) { return v / (1.0f + __expf(-v)); }

DEV float redmax16(float v) {
  v = fmaxf(v, __shfl_xor(v, 1));
  v = fmaxf(v, __shfl_xor(v, 2));
  v = fmaxf(v, __shfl_xor(v, 4));
  v = fmaxf(v, __shfl_xor(v, 8));
  return v;
}
DEV float redsum16(float v) {
  v += __shfl_xor(v, 1);
  v += __shfl_xor(v, 2);
  v += __shfl_xor(v, 4);
  v += __shfl_xor(v, 8);
  return v;
}

// window permutation: p (= y*128+x) -> window-major ordinal
DEV int wperm(int p) {
  int y = p >> 7, x = p & 127;
  return ((((y >> 3) << 4) + (x >> 3)) << 6) + ((y & 7) << 3) + (x & 7);
}

// async global -> LDS, 16B per lane. LDS dest wave-uniform base + lane*16.
DEV void gload16(const u16* g, u16* l) {
  __builtin_amdgcn_global_load_lds(
      (const __attribute__((address_space(1))) uint32_t*)(g),
      (__attribute__((address_space(3))) uint32_t*)(l), 16, 0, 0);
}

// -------- merged weight converts f32 -> bf16 --------
struct WConv {
  const float* s0; const float* s1; const float* s2; const float* s3;
  const float* s4; const float* s5; const float* s6;
  u16* d0; u16* d1; u16* d2; u16* d3; u16* d4; u16* d5; u16* d6;
};
__global__ void k_conv_all(WConv wc) {
  int i = blockIdx.x * 256 + threadIdx.x;  // float4 index, total 180224
  if (i >= 180224) return;
  const float* sp[7] = {wc.s0, wc.s1, wc.s2, wc.s3, wc.s4, wc.s5, wc.s6};
  u16* dp[7] = {wc.d0, wc.d1, wc.d2, wc.d3, wc.d4, wc.d5, wc.d6};
  const int n4[7] = {16384, 16384, 32768, 32768, 49152, 16384, 16384};
  int rem = i, seg = 0;
#pragma unroll
  for (int s = 0; s < 7; ++s) {
    if (rem < n4[s]) { seg = s; break; }
    rem -= n4[s];
  }
  float4 v = ((const float4*)sp[seg])[rem];
  u16 t[4] = {f2b(v.x), f2b(v.y), f2b(v.z), f2b(v.w)};
  *(uint2*)(dp[seg] + (rem << 2)) = *(uint2*)t;
}

// -------- block reduce (sum,sumsq) over 256 threads --------
DEV void breduce2(float& a, float& b, float* red, int tid) {
#pragma unroll
  for (int off = 32; off > 0; off >>= 1) {
    a += __shfl_down(a, off);
    b += __shfl_down(b, off);
  }
  int lane = tid & 63, wv = tid >> 6;
  if (lane == 0) { red[wv * 2] = a; red[wv * 2 + 1] = b; }
  __syncthreads();
  a = red[0] + red[2] + red[4] + red[6];
  b = red[1] + red[3] + red[5] + red[7];
}

// -------- GroupNorm stats (+ optional bf16 copy of x) --------
template <int XB>
__global__ void k_gn_partial(const float* __restrict__ x, float* __restrict__ partials,
                             u16* __restrict__ xb) {
  __shared__ float red[8];
  int chunk = blockIdx.x;
  size_t base4 = ((size_t)chunk) << 12;
  const float4* x4 = (const float4*)x;
  float a = 0.f, b = 0.f;
#pragma unroll 4
  for (int i = 0; i < 16; ++i) {
    size_t idx = base4 + (i << 8) + threadIdx.x;
    float4 v = x4[idx];
    a += v.x + v.y + v.z + v.w;
    b += v.x * v.x + v.y * v.y + v.z * v.z + v.w * v.w;
    if (XB) {
      u16 t[4] = {f2b(v.x), f2b(v.y), f2b(v.z), f2b(v.w)};
      *(uint2*)(xb + (idx << 2)) = *(uint2*)t;
    }
  }
  breduce2(a, b, red, threadIdx.x);
  if (threadIdx.x == 0) { partials[chunk * 2] = a; partials[chunk * 2 + 1] = b; }
}

__global__ void k_gn_final(const float* __restrict__ partials, float* __restrict__ stats) {
  int g = blockIdx.x, lane = threadIdx.x;
  float a = partials[(((g << 6) + lane) << 1)];
  float b = partials[(((g << 6) + lane) << 1) + 1];
#pragma unroll
  for (int off = 32; off > 0; off >>= 1) {
    a += __shfl_down(a, off);
    b += __shfl_down(b, off);
  }
  if (lane == 0) {
    float mean = a * (1.f / 1048576.f);
    float var = b * (1.f / 1048576.f) - mean * mean;
    stats[g << 1] = mean;
    stats[(g << 1) + 1] = rsqrtf(var + 1e-5f);
  }
}

// -------- style linear --------
__global__ void k_style(const float* __restrict__ sc, const float* __restrict__ gw,
                        const float* __restrict__ gb, const float* __restrict__ sw,
                        const float* __restrict__ sb, float* __restrict__ gp,
                        float* __restrict__ stok) {
  __shared__ float row[512];
  int b = blockIdx.y, part = blockIdx.x, tid = threadIdx.x;
  row[tid] = sc[(b << 9) + tid];
  row[tid + 256] = sc[(b << 9) + tid + 256];
  __syncthreads();
  if (part < 2) {
    int o = (part << 8) + tid;
    float s = gb[o];
    const float* wr = gw + ((size_t)o << 9);
#pragma unroll 8
    for (int j = 0; j < 512; ++j) s += row[j] * wr[j];
    gp[(b << 9) + o] = s;
  } else {
    float s = sb[tid];
    const float* wr = sw + ((size_t)tid << 9);
#pragma unroll 8
    for (int j = 0; j < 512; ++j) s += row[j] * wr[j];
    stok[(b << 8) + tid] = s;
  }
}

// -------- style tokens + LN --------
__global__ void k_styk(const float* __restrict__ tb, const float* __restrict__ stok,
                       const float* __restrict__ g, const float* __restrict__ bt,
                       float* __restrict__ styk) {
  __shared__ float red[8];
  int r = blockIdx.x;
  int b = r >> 6, t = r & 63;
  int c = threadIdx.x;
  float v = tb[(t << 8) + c] + stok[(b << 8) + c];
  float a = v, bb = v * v;
  breduce2(a, bb, red, c);
  float mean = a * (1.f / 256.f);
  float var = bb * (1.f / 256.f) - mean * mean;
  float rs = rsqrtf(var + 1e-5f);
  styk[((size_t)r << 8) + c] = (v - mean) * rs * g[c] + bt[c];
}

// -------- K/V projections of style tokens -> bf16 --------
__global__ void k_kv(const float* __restrict__ styk, const float* __restrict__ kw,
                     const float* __restrict__ kb, const float* __restrict__ vw,
                     const float* __restrict__ vb, u16* __restrict__ kmat,
                     u16* __restrict__ vmat) {
  __shared__ float srow[256];
  int r = blockIdx.x, c = threadIdx.x;
  srow[c] = styk[((size_t)r << 8) + c];
  __syncthreads();
  float sk = kb[c], sv = vb[c];
  const float* kr = kw + ((size_t)c << 8);
  const float* vr = vw + ((size_t)c << 8);
#pragma unroll 8
  for (int j = 0; j < 256; ++j) { sk += srow[j] * kr[j]; sv += srow[j] * vr[j]; }
  kmat[((size_t)r << 8) + c] = f2b(sk);
  vmat[((size_t)r << 8) + c] = f2b(sv);
}

// -------- pos hidden --------
__global__ void k_posh(const float* __restrict__ w1, const float* __restrict__ b1,
                       u16* __restrict__ posh) {
  int i = blockIdx.x * 256 + threadIdx.x;
  int stride = gridDim.x * 256;
  for (; i < 16384 * 256; i += stride) {
    int p = i >> 8, c = i & 255;
    int y = p >> 7, x = p & 127;
    float gx = -1.f + 2.f * (float)x / 127.f;
    float gy = -1.f + 2.f * (float)y / 127.f;
    float v = gx * w1[c << 1] + gy * w1[(c << 1) + 1] + b1[c];
    posh[i] = f2b(silu_f(v));
  }
}

// ======== MFMA bf16 GEMM (NT), m97 structure + XCD-grouped swizzle ========
// SPLIT=1 (qkv): outputs go to o0/o1/o2 (ldc 256) with WINDOW-PERMUTED rows.
template <int ACT, int BIAS, int RES, int SPLIT>
__global__ __launch_bounds__(256, 2) void k_gemm2(
    const u16* __restrict__ A, const u16* __restrict__ Bw,
    const float* __restrict__ bias, const u16* __restrict__ res,
    u16* __restrict__ o0, u16* __restrict__ o1, u16* __restrict__ o2,
    int M, int N, int K) {
  __shared__ __align__(16) u16 lds[17408];
  u16* sA = lds;
  u16* sB = lds + 4096;
  const int tid = threadIdx.x;
  const int lane = tid & 63, wv = tid >> 6;
  // XCD-grouped swizzle: same-A blocks -> same XCD, adjacent in time.
  const int nx = gridDim.x;
  const int L = blockIdx.x + nx * blockIdx.y;
  const int xcd = L & 7;
  const int t = L >> 3;
  const int nblk = t % nx;
  const int mblk = ((t / nx) << 3) + xcd;
  const int m0 = mblk << 7, n0 = nblk << 7;
  const int l15 = lane & 15, lg = lane >> 4;
  const int wr = wv >> 1, wc = wv & 1;

  const int gofs = (((lane & 3) ^ ((lane >> 3) & 3)) << 3);
  const int lrow = lane >> 2;
  const u16* Ag0 = A + (size_t)(m0 + (wv << 5) + lrow) * K + gofs;
  const u16* Ag1 = A + (size_t)(m0 + (wv << 5) + 16 + lrow) * K + gofs;
  const u16* Bg0 = Bw + (size_t)(n0 + (wv << 5) + lrow) * K + gofs;
  const u16* Bg1 = Bw + (size_t)(n0 + (wv << 5) + 16 + lrow) * K + gofs;
  u16* lA0 = sA + (wv << 10);
  u16* lA1 = sA + (wv << 10) + 512;
  u16* lB0 = sB + (wv << 10);
  u16* lB1 = sB + (wv << 10) + 512;

  const int roff = l15 * 32 + (((lg ^ ((l15 >> 1) & 3))) << 3);
  const int abase = (wr << 6) * 32;
  const int bbase = (wc << 6) * 32;

  f32x4 acc[4][4];
  f32x4 zz = {0.f, 0.f, 0.f, 0.f};
#pragma unroll
  for (int mi = 0; mi < 4; ++mi)
#pragma unroll
    for (int ni = 0; ni < 4; ++ni) acc[mi][ni] = zz;

  for (int kt = 0; kt < K; kt += 32) {
    __syncthreads();
    gload16(Ag0 + kt, lA0);
    gload16(Ag1 + kt, lA1);
    gload16(Bg0 + kt, lB0);
    gload16(Bg1 + kt, lB1);
    __syncthreads();
    bf16x8 af[4], bfv[4];
#pragma unroll
    for (int mi = 0; mi < 4; ++mi) af[mi] = *(const bf16x8*)&sA[abase + mi * 512 + roff];
#pragma unroll
    for (int ni = 0; ni < 4; ++ni) bfv[ni] = *(const bf16x8*)&sB[bbase + ni * 512 + roff];
#pragma unroll
    for (int mi = 0; mi < 4; ++mi)
#pragma unroll
      for (int ni = 0; ni < 4; ++ni)
        acc[mi][ni] = __builtin_amdgcn_mfma_f32_16x16x32_bf16(af[mi], bfv[ni], acc[mi][ni], 0, 0, 0);
  }

  float bv[4];
#pragma unroll
  for (int ni = 0; ni < 4; ++ni)
    bv[ni] = BIAS ? bias[n0 + (wc << 6) + (ni << 4) + l15] : 0.0f;
  __syncthreads();
  const int lg4 = lg << 2;
#pragma unroll
  for (int mi = 0; mi < 4; ++mi) {
#pragma unroll
    for (int ni = 0; ni < 4; ++ni) {
#pragma unroll
      for (int r = 0; r < 4; ++r) {
        int row = (wr << 6) + (mi << 4) + lg4 + r;
        int col = (wc << 6) + (ni << 4) + l15;
        float v = acc[mi][ni][r] + bv[ni];
        if (ACT == 1) v = silu_f(v);
        lds[row * 136 + col] = f2b(v);
      }
    }
  }
  __syncthreads();
  u16* obase;
  int cb, ldc;
  if (SPLIT) {
    int sel = n0 >> 8;
    obase = sel == 0 ? o0 : (sel == 1 ? o1 : o2);
    cb = n0 & 255;
    ldc = 256;
  } else {
    obase = o0;
    cb = n0;
    ldc = N;
  }
#pragma unroll
  for (int i = 0; i < 8; ++i) {
    int flat = (i << 8) + tid;
    int row = flat >> 4, c8 = (flat & 15) << 3;
    uint4 vv = *(const uint4*)&lds[row * 136 + c8];
    size_t oi;
    if (SPLIT) {
      // window-permuted output rows for q/k/v
      int m = m0 + row;
      int orow = (m & ~16383) | wperm(m & 16383);
      oi = (size_t)orow * 256 + cb + c8;
    } else {
      oi = (size_t)(m0 + row) * ldc + cb + c8;
    }
    if (RES) {
      uint4 rr = *(const uint4*)(res + oi);
      float a8[8], r8[8];
      up8(vv, a8);
      up8(rr, r8);
      u16 t8[8];
#pragma unroll
      for (int e = 0; e < 8; ++e) t8[e] = f2b(a8[e] + r8[e]);
      vv = *(const uint4*)t8;
    }
    *(uint4*)(obase + oi) = vv;
  }
}

// -------- fused: GN-normalize + transpose + pos_emb + qn LayerNorm -> tokq --------
template <int XB>
__global__ __launch_bounds__(256) void k_tokpe2(
    const float* __restrict__ x, const u16* __restrict__ xb,
    const float* __restrict__ stats, const u16* __restrict__ pe,
    const float* __restrict__ qg, const float* __restrict__ qb2,
    u16* __restrict__ tokq) {
  __shared__ u16 T[256 * 72];
  __shared__ float red[64][8];
  const int tid = threadIdx.x;
  const int p0 = blockIdx.x << 6, b = blockIdx.y;
  {
    const int c = tid;
    const int g = (b << 2) + (c >> 6);
    const float mu = stats[g << 1], rs = stats[(g << 1) + 1];
    const size_t base = (((size_t)(b << 8) + c) << 14) + p0;
#pragma unroll
    for (int j8 = 0; j8 < 8; ++j8) {
      float f[8];
      if (XB) {
        up8(*(const uint4*)(xb + base + (j8 << 3)), f);
      } else {
        float4 v0 = *(const float4*)(x + base + (j8 << 3));
        float4 v1 = *(const float4*)(x + base + (j8 << 3) + 4);
        f[0] = v0.x; f[1] = v0.y; f[2] = v0.z; f[3] = v0.w;
        f[4] = v1.x; f[5] = v1.y; f[6] = v1.z; f[7] = v1.w;
      }
      u16 t8[8];
#pragma unroll
      for (int e = 0; e < 8; ++e) t8[e] = f2b((f[e] - mu) * rs);
      *(uint4*)&T[c * 72 + (j8 << 3)] = *(uint4*)t8;
    }
  }
  __syncthreads();
  const int p = tid & 63, cq = tid >> 6;
  const size_t pebase = (((size_t)(p0 + p)) << 8) + (cq << 6);
  float vbuf[64];
  float a = 0.f, s = 0.f;
#pragma unroll
  for (int q = 0; q < 8; ++q) {
    float pf[8];
    up8(*(const uint4*)(pe + pebase + (q << 3)), pf);
#pragma unroll
    for (int e = 0; e < 8; ++e) {
      int j = (q << 3) + e;
      float v = b2f(T[((cq << 6) + j) * 72 + p]) + pf[e];
      vbuf[j] = v;
      a += v; s += v * v;
    }
  }
  red[p][cq << 1] = a;
  red[p][(cq << 1) + 1] = s;
  __syncthreads();
  float sa = red[p][0] + red[p][2] + red[p][4] + red[p][6];
  float ss = red[p][1] + red[p][3] + red[p][5] + red[p][7];
  float mean = sa * (1.f / 256.f);
  float var = ss * (1.f / 256.f) - mean * mean;
  float rsg = rsqrtf(var + 1e-5f);
  const size_t orow = (((size_t)(b << 14) + p0 + p) << 8) + (cq << 6);
#pragma unroll
  for (int q = 0; q < 8; ++q) {
    u16 t8[8];
#pragma unroll
    for (int e = 0; e < 8; ++e) {
      int j = (q << 3) + e;
      t8[e] = f2b((vbuf[j] - mean) * rsg * qg[(cq << 6) + j] + qb2[(cq << 6) + j]);
    }
    *(uint4*)(tokq + orow + (q << 3)) = *(uint4*)t8;
  }
}

// -------- vectorized row LayerNorm (256) --------
__global__ __launch_bounds__(256) void k_rowln8(const u16* __restrict__ in,
                                                const float* __restrict__ g,
                                                const float* __restrict__ bt,
                                                u16* __restrict__ out) {
  __shared__ float gs[256], bs[256];
  int tid = threadIdx.x;
  gs[tid] = g[tid];
  bs[tid] = bt[tid];
  __syncthreads();
  size_t base = (((size_t)(blockIdx.x << 5) + (tid >> 3)) << 8) + ((tid & 7) << 5);
  float v[32];
#pragma unroll
  for (int q = 0; q < 4; ++q) up8(*(const uint4*)(in + base + (q << 3)), &v[q << 3]);
  float a = 0.f, b = 0.f;
#pragma unroll
  for (int j = 0; j < 32; ++j) { a += v[j]; b += v[j] * v[j]; }
#pragma unroll
  for (int m = 1; m <= 4; m <<= 1) { a += __shfl_xor(a, m); b += __shfl_xor(b, m); }
  float mean = a * (1.f / 256.f);
  float var = b * (1.f / 256.f) - mean * mean;
  float rs = rsqrtf(var + 1e-5f);
  int c0 = (tid & 7) << 5;
#pragma unroll
  for (int q = 0; q < 4; ++q) {
    u16 tmp[8];
#pragma unroll
    for (int e = 0; e < 8; ++e) {
      int j = (q << 3) + e;
      tmp[e] = f2b((v[j] - mean) * rs * gs[c0 + j] + bs[c0 + j]);
    }
    *(uint4*)(out + base + (q << 3)) = *(uint4*)tmp;
  }
}

// -------- MFMA cross attention (round-6 barriered version) --------
__global__ __launch_bounds__(256, 2) void k_cross_mfma(
    const u16* __restrict__ qmat, const u16* __restrict__ kmat,
    const u16* __restrict__ vmat, u16* __restrict__ attn_out) {
  __shared__ u16 Kl[64 * 72];
  __shared__ u16 Vt[64 * 72];
  __shared__ u16 Pl[4][64 * 72];
  const int tid = threadIdx.x;
  const int lane = tid & 63, wv = tid >> 6;
  const int l15 = lane & 15, lg = lane >> 4;
  const int b = blockIdx.z, h = blockIdx.y;
  const int q0 = blockIdx.x << 8;
  for (int c = tid; c < 512; c += 256) {
    int t = c >> 3, dg = (c & 7) << 3;
    size_t src = (((size_t)(b << 6) + t) << 8) + (h << 6) + dg;
    *(uint4*)&Kl[t * 72 + dg] = *(const uint4*)(kmat + src);
    uint4 vv = *(const uint4*)(vmat + src);
    const u16* pv = (const u16*)&vv;
#pragma unroll
    for (int e = 0; e < 8; ++e) Vt[(dg + e) * 72 + t] = pv[e];
  }
  __syncthreads();
  const size_t qrow0 = (size_t)(b << 14) + q0 + (wv << 6);
  f32x4 acc[4][4];
  f32x4 zz = {0.f, 0.f, 0.f, 0.f};
#pragma unroll
  for (int mi = 0; mi < 4; ++mi)
#pragma unroll
    for (int ni = 0; ni < 4; ++ni) acc[mi][ni] = zz;
#pragma unroll
  for (int ks = 0; ks < 2; ++ks) {
    bf16x8 a[4], bbf[4];
#pragma unroll
    for (int mi = 0; mi < 4; ++mi)
      a[mi] = *(const bf16x8*)(qmat + ((qrow0 + (mi << 4) + l15) << 8) + (h << 6) +
                               (ks << 5) + (lg << 3));
#pragma unroll
    for (int ni = 0; ni < 4; ++ni)
      bbf[ni] = *(const bf16x8*)&Kl[((ni << 4) + l15) * 72 + (ks << 5) + (lg << 3)];
#pragma unroll
    for (int mi = 0; mi < 4; ++mi)
#pragma unroll
      for (int ni = 0; ni < 4; ++ni)
        acc[mi][ni] = __builtin_amdgcn_mfma_f32_16x16x32_bf16(a[mi], bbf[ni], acc[mi][ni], 0, 0, 0);
  }
  const float SC = 0.25f;
#pragma unroll
  for (int mi = 0; mi < 4; ++mi) {
#pragma unroll
    for (int r = 0; r < 4; ++r) {
      float rm = acc[mi][0][r];
#pragma unroll
      for (int ni = 1; ni < 4; ++ni) rm = fmaxf(rm, acc[mi][ni][r]);
      rm = redmax16(rm);
      float pv[4];
      float rs = 0.f;
#pragma unroll
      for (int ni = 0; ni < 4; ++ni) {
        pv[ni] = __expf((acc[mi][ni][r] - rm) * SC);
        rs += pv[ni];
      }
      rs = redsum16(rs);
      float inv = 1.f / rs;
      int row = (mi << 4) + (lg << 2) + r;
#pragma unroll
      for (int ni = 0; ni < 4; ++ni)
        Pl[wv][row * 72 + (ni << 4) + l15] = f2b(pv[ni] * inv);
    }
  }
  __syncthreads();
  f32x4 o[4][4];
#pragma unroll
  for (int mi = 0; mi < 4; ++mi)
#pragma unroll
    for (int ni = 0; ni < 4; ++ni) o[mi][ni] = zz;
#pragma unroll
  for (int ks = 0; ks < 2; ++ks) {
    bf16x8 a[4], bbf[4];
#pragma unroll
    for (int mi = 0; mi < 4; ++mi)
      a[mi] = *(const bf16x8*)&Pl[wv][((mi << 4) + l15) * 72 + (ks << 5) + (lg << 3)];
#pragma unroll
    for (int ni = 0; ni < 4; ++ni)
      bbf[ni] = *(const bf16x8*)&Vt[((ni << 4) + l15) * 72 + (ks << 5) + (lg << 3)];
#pragma unroll
    for (int mi = 0; mi < 4; ++mi)
#pragma unroll
      for (int ni = 0; ni < 4; ++ni)
        o[mi][ni] = __builtin_amdgcn_mfma_f32_16x16x32_bf16(a[mi], bbf[ni], o[mi][ni], 0, 0, 0);
  }
  __syncthreads();
#pragma unroll
  for (int mi = 0; mi < 4; ++mi)
#pragma unroll
    for (int ni = 0; ni < 4; ++ni)
#pragma unroll
      for (int r = 0; r < 4; ++r)
        Pl[wv][((mi << 4) + (lg << 2) + r) * 72 + (ni << 4) + l15] = f2b(o[mi][ni][r]);
  __syncthreads();
  const int l8r = lane >> 3, l8c = lane & 7;
#pragma unroll
  for (int it = 0; it < 8; ++it) {
    int row = (it << 3) + l8r;
    uint4 vv = *(const uint4*)&Pl[wv][row * 72 + (l8c << 3)];
    *(uint4*)(attn_out + ((qrow0 + row) << 8) + (h << 6) + (l8c << 3)) = vv;
  }
}

// -------- MFMA window attention (round-6 structure, window-permuted layout) --------
// q/k/v/wout rows are window-major: token t of window w at row w*64+t (32KB/window).
__global__ __launch_bounds__(256, 2) void k_win_mfma(
    const u16* __restrict__ qb, const u16* __restrict__ kbuf,
    const u16* __restrict__ vbuf, u16* __restrict__ wout) {
  __shared__ u16 Vt[4][32 * 72];
  __shared__ u16 Pl[4][64 * 72];
  const int tid = threadIdx.x;
  const int lane = tid & 63, wv = tid >> 6;
  const int l15 = lane & 15, lg = lane >> 4;
  const int win = blockIdx.x, b = blockIdx.y;
  const size_t rowbase = (size_t)(b << 14) + (win << 6);
  const float SC = 0.17677669529663687f;
  f32x4 zz = {0.f, 0.f, 0.f, 0.f};
#pragma unroll 1
  for (int h2 = 0; h2 < 2; ++h2) {
    const int h = (wv << 1) + h2;
    const int co = h << 5;
    // stage V^T: lane loads its token (contiguous rows)
    {
      const u16* src = vbuf + ((rowbase + lane) << 8) + co;
#pragma unroll
      for (int c = 0; c < 4; ++c) {
        uint4 vv = *(const uint4*)(src + (c << 3));
        const u16* pe = (const u16*)&vv;
#pragma unroll
        for (int e = 0; e < 8; ++e) Vt[wv][((c << 3) + e) * 72 + lane] = pe[e];
      }
    }
    // S = Q K^T  (M=64, N=64, K=32)
    f32x4 acc[4][4];
#pragma unroll
    for (int mi = 0; mi < 4; ++mi)
#pragma unroll
      for (int ni = 0; ni < 4; ++ni) acc[mi][ni] = zz;
    {
      bf16x8 a[4], bbf[4];
#pragma unroll
      for (int mi = 0; mi < 4; ++mi)
        a[mi] = *(const bf16x8*)(qb + ((rowbase + (mi << 4) + l15) << 8) + co + (lg << 3));
#pragma unroll
      for (int ni = 0; ni < 4; ++ni)
        bbf[ni] = *(const bf16x8*)(kbuf + ((rowbase + (ni << 4) + l15) << 8) + co + (lg << 3));
#pragma unroll
      for (int mi = 0; mi < 4; ++mi)
#pragma unroll
        for (int ni = 0; ni < 4; ++ni)
          acc[mi][ni] = __builtin_amdgcn_mfma_f32_16x16x32_bf16(a[mi], bbf[ni], acc[mi][ni], 0, 0, 0);
    }
    // softmax + write P
#pragma unroll
    for (int mi = 0; mi < 4; ++mi) {
#pragma unroll
      for (int r = 0; r < 4; ++r) {
        float rm = acc[mi][0][r];
#pragma unroll
        for (int ni = 1; ni < 4; ++ni) rm = fmaxf(rm, acc[mi][ni][r]);
        rm = redmax16(rm);
        float pv[4];
        float rs = 0.f;
#pragma unroll
        for (int ni = 0; ni < 4; ++ni) {
          pv[ni] = __expf((acc[mi][ni][r] - rm) * SC);
          rs += pv[ni];
        }
        rs = redsum16(rs);
        float inv = 1.f / rs;
        int row = (mi << 4) + (lg << 2) + r;
#pragma unroll
        for (int ni = 0; ni < 4; ++ni)
          Pl[wv][row * 72 + (ni << 4) + l15] = f2b(pv[ni] * inv);
      }
    }
    __syncthreads();
    // O = P V  (M=64, N=32, K=64)
    f32x4 o[4][2];
#pragma unroll
    for (int mi = 0; mi < 4; ++mi)
#pragma unroll
      for (int ni = 0; ni < 2; ++ni) o[mi][ni] = zz;
#pragma unroll
    for (int ks = 0; ks < 2; ++ks) {
      bf16x8 a[4], bbf[2];
#pragma unroll
      for (int mi = 0; mi < 4; ++mi)
        a[mi] = *(const bf16x8*)&Pl[wv][((mi << 4) + l15) * 72 + (ks << 5) + (lg << 3)];
#pragma unroll
      for (int ni = 0; ni < 2; ++ni)
        bbf[ni] = *(const bf16x8*)&Vt[wv][((ni << 4) + l15) * 72 + (ks << 5) + (lg << 3)];
#pragma unroll
      for (int mi = 0; mi < 4; ++mi)
#pragma unroll
        for (int ni = 0; ni < 2; ++ni)
          o[mi][ni] = __builtin_amdgcn_mfma_f32_16x16x32_bf16(a[mi], bbf[ni], o[mi][ni], 0, 0, 0);
    }
    __syncthreads();
    // stage O -> Pl, coalesced write (contiguous rows)
#pragma unroll
    for (int mi = 0; mi < 4; ++mi)
#pragma unroll
      for (int ni = 0; ni < 2; ++ni)
#pragma unroll
        for (int r = 0; r < 4; ++r)
          Pl[wv][((mi << 4) + (lg << 2) + r) * 72 + (ni << 4) + l15] = f2b(o[mi][ni][r]);
    __syncthreads();
#pragma unroll
    for (int it = 0; it < 4; ++it) {
      int row = (it << 4) + (lane >> 2);
      int cg = (lane & 3) << 3;
      uint4 vv = *(const uint4*)&Pl[wv][row * 72 + cg];
      *(uint4*)(wout + ((rowbase + row) << 8) + co + cg) = vv;
    }
    __syncthreads();
  }
}

// -------- xrt = roll(h,(-4,-4)) NHWC bf16 --------
template <int XB>
__global__ void k_xrt(const float* __restrict__ x, const u16* __restrict__ xb,
                      const u16* __restrict__ sc2, const float* __restrict__ stats,
                      const float* __restrict__ gp, const float* __restrict__ gamma,
                      u16* __restrict__ xrt) {
  __shared__ float A[64][33];
  __shared__ float Bt[32][65];
  int p0 = blockIdx.x << 6, c0 = blockIdx.y << 5, b = blockIdx.z;
  int tid = threadIdx.x;
#pragma unroll
  for (int i = 0; i < 8; ++i) {
    int flat = (i << 8) + tid;
    int pi = flat >> 5, ci = flat & 31;
    A[pi][ci] = b2f(sc2[(((size_t)(b << 14) + p0 + pi) << 8) + c0 + ci]);
  }
  __syncthreads();
#pragma unroll
  for (int i = 0; i < 8; ++i) {
    int flat = (i << 8) + tid;
    int cc = flat >> 6, px = flat & 63;
    int cch = c0 + cc;
    int g = (b << 2) + (cch >> 6);
    float mu = stats[g << 1], rs = stats[(g << 1) + 1];
    size_t xi = (((size_t)(b << 8) + cch) << 14) + p0 + px;
    float xv = XB ? b2f(xb[xi]) : x[xi];
    float val = xv + (xv - mu) * rs * gp[(b << 9) + cch] + gp[(b << 9) + 256 + cch] +
                A[px][cc] * gamma[cch];
    Bt[cc][px] = val;
  }
  __syncthreads();
#pragma unroll
  for (int i = 0; i < 8; ++i) {
    int flat = (i << 8) + tid;
    int xi2 = flat >> 5, ci = flat & 31;
    int p = p0 + xi2;
    int yy = p >> 7, xx = p & 127;
    int pr = (((yy + 124) & 127) << 7) + ((xx + 124) & 127);
    xrt[(((size_t)(b << 14) + pr) << 8) + c0 + ci] = f2b(Bt[ci][xi2]);
  }
}

// -------- final: dout = h (from xr) + rollback(out2, window-permuted rows) --------
__global__ void k_final2(const u16* __restrict__ xr, const u16* __restrict__ out2,
                         float* __restrict__ dout) {
  __shared__ float L[64][33];
  int bx = blockIdx.x;
  int y = bx >> 1, x0 = (bx & 1) << 6;
  int c0 = blockIdx.y << 5, b = blockIdx.z;
  int tid = threadIdx.x;
#pragma unroll
  for (int i = 0; i < 8; ++i) {
    int flat = (i << 8) + tid;
    int xi = flat >> 5, ci = flat & 31;
    int xx = x0 + xi;
    int pr = (((y + 124) & 127) << 7) + ((xx + 124) & 127);
    size_t ii = (((size_t)(b << 14) + pr) << 8) + c0 + ci;
    size_t ii2 = (((size_t)(b << 14) + wperm(pr)) << 8) + c0 + ci;
    L[xi][ci] = b2f(xr[ii]) + b2f(out2[ii2]);
  }
  __syncthreads();
#pragma unroll
  for (int i = 0; i < 8; ++i) {
    int flat = (i << 8) + tid;
    int cc = flat >> 6, xi2 = flat & 63;
    size_t idx = (((size_t)(b << 8) + c0 + cc) << 14) + (y << 7) + x0 + xi2;
    dout[idx] = L[xi2][cc];
  }
}

extern "C" void kernel_launch(void* const* d_in, const int* in_sizes, int n_in,
                              void* d_out, int out_size, void* d_ws, size_t ws_size,
                              hipStream_t stream) {
  (void)in_sizes; (void)n_in; (void)out_size;
  const float* x = (const float*)d_in[0];
  const float* style = (const float*)d_in[1];
  const float* qkv_w = (const float*)d_in[2];
  const float* spat_w = (const float*)d_in[3];
  const float* gproj_w = (const float*)d_in[4];
  const float* gproj_b = (const float*)d_in[5];
  const float* tokens_basis = (const float*)d_in[6];
  const float* sproj_w = (const float*)d_in[7];
  const float* sproj_b = (const float*)d_in[8];
  const float* pos_w1 = (const float*)d_in[9];
  const float* pos_b1 = (const float*)d_in[10];
  const float* pos_w2 = (const float*)d_in[11];
  const float* pos_b2 = (const float*)d_in[12];
  const float* q_w = (const float*)d_in[13];
  const float* q_b = (const float*)d_in[14];
  const float* k_w = (const float*)d_in[15];
  const float* k_b = (const float*)d_in[16];
  const float* v_w = (const float*)d_in[17];
  const float* v_b = (const float*)d_in[18];
  const float* o_w = (const float*)d_in[19];
  const float* o_b = (const float*)d_in[20];
  const float* ffn_w1 = (const float*)d_in[21];
  const float* ffn_b1 = (const float*)d_in[22];
  const float* ffn_w2 = (const float*)d_in[23];
  const float* ffn_b2 = (const float*)d_in[24];
  const float* tn_g = (const float*)d_in[25];
  const float* tn_b = (const float*)d_in[26];
  const float* qn_g = (const float*)d_in[27];
  const float* qn_b = (const float*)d_in[28];
  const float* fn_g = (const float*)d_in[29];
  const float* fn_b = (const float*)d_in[30];
  const float* gamma = (const float*)d_in[31];
  float* dout = (float*)d_out;

  char* w = (char*)d_ws;
  size_t off = 0;
  auto alloc = [&](size_t sz) {
    char* p = w + off;
    off += (sz + 255) & ~(size_t)255;
    return (void*)p;
  };
  float* partials = (float*)alloc(1024 * 2 * 4);
  float* stats = (float*)alloc(32 * 4);
  float* gp = (float*)alloc(4 * 512 * 4);
  float* stok = (float*)alloc(4 * 256 * 4);
  float* styk = (float*)alloc(4 * 64 * 256 * 4);
  u16* kmat = (u16*)alloc(4 * 64 * 256 * 2);
  u16* vmat = (u16*)alloc(4 * 64 * 256 * 2);
  u16* wb_q = (u16*)alloc(65536 * 2);
  u16* wb_o = (u16*)alloc(65536 * 2);
  u16* wb_w1 = (u16*)alloc(131072 * 2);
  u16* wb_w2 = (u16*)alloc(131072 * 2);
  u16* wb_qkv = (u16*)alloc(196608 * 2);
  u16* wb_sp = (u16*)alloc(65536 * 2);
  u16* wb_p2 = (u16*)alloc(65536 * 2);
  const size_t SLOT = (size_t)65536 * 256 * 2;  // 32 MiB
  u16* S0 = (u16*)alloc(SLOT);
  u16* S1 = (u16*)alloc(SLOT);
  u16* S2 = (u16*)alloc(SLOT);
  size_t off_base = off;
  u16* xb = (u16*)alloc((size_t)16777216 * 2);  // 32 MiB bf16 copy of x
  if (ws_size < off_base) return;
  const int XB = (ws_size >= off) ? 1 : 0;

  // d_out is exactly 64 MiB: ffn_h uses all of it; kwin/vwin split it.
  u16* ffn_h = (u16*)d_out;                            // [0, 64 MiB)
  u16* kwin = (u16*)d_out;                             // [0, 32 MiB)
  u16* vwin = (u16*)d_out + (size_t)65536 * 256;       // [32, 64 MiB)

  WConv wc = {q_w, o_w, ffn_w1, ffn_w2, qkv_w, spat_w, pos_w2,
              wb_q, wb_o, wb_w1, wb_w2, wb_qkv, wb_sp, wb_p2};
  k_conv_all<<<704, 256, 0, stream>>>(wc);

  if (XB) k_gn_partial<1><<<1024, 256, 0, stream>>>(x, partials, xb);
  else k_gn_partial<0><<<1024, 256, 0, stream>>>(x, partials, xb);
  k_gn_final<<<16, 64, 0, stream>>>(partials, stats);

  k_style<<<dim3(3, 4), 256, 0, stream>>>(style, gproj_w, gproj_b, sproj_w, sproj_b, gp, stok);
  k_styk<<<256, 256, 0, stream>>>(tokens_basis, stok, tn_g, tn_b, styk);
  k_kv<<<256, 256, 0, stream>>>(styk, k_w, k_b, v_w, v_b, kmat, vmat);

  k_posh<<<4096, 256, 0, stream>>>(pos_w1, pos_b1, S0);
  k_gemm2<0, 1, 0, 0><<<dim3(2, 128), 256, 0, stream>>>(S0, wb_p2, pos_b2, nullptr,
                                                        S1, nullptr, nullptr, 16384, 256, 256);

  // fused GN-transpose + pos_emb + qn LN -> tokq (S2)
  if (XB) k_tokpe2<1><<<dim3(256, 4), 256, 0, stream>>>(x, xb, stats, S1, qn_g, qn_b, S2);
  else k_tokpe2<0><<<dim3(256, 4), 256, 0, stream>>>(x, xb, stats, S1, qn_g, qn_b, S2);

  k_gemm2<0, 1, 0, 0><<<dim3(2, 512), 256, 0, stream>>>(S2, wb_q, q_b, nullptr,
                                                        S1, nullptr, nullptr, 65536, 256, 256);
  k_cross_mfma<<<dim3(64, 4, 4), 256, 0, stream>>>(S1, kmat, vmat, S0);
  k_gemm2<0, 1, 0, 0><<<dim3(2, 512), 256, 0, stream>>>(S0, wb_o, o_b, nullptr,
                                                        S2, nullptr, nullptr, 65536, 256, 256);

  k_rowln8<<<2048, 256, 0, stream>>>(S2, fn_g, fn_b, S1);
  k_gemm2<1, 1, 0, 0><<<dim3(4, 512), 256, 0, stream>>>(S1, wb_w1, ffn_b1, nullptr,
                                                        ffn_h, nullptr, nullptr, 65536, 512, 256);
  k_gemm2<0, 1, 1, 0><<<dim3(2, 512), 256, 0, stream>>>(ffn_h, wb_w2, ffn_b2, S2,
                                                        S0, nullptr, nullptr, 65536, 256, 512);

  if (XB) k_xrt<1><<<dim3(256, 8, 4), 256, 0, stream>>>(x, xb, S0, stats, gp, gamma, S1);
  else k_xrt<0><<<dim3(256, 8, 4), 256, 0, stream>>>(x, xb, S0, stats, gp, gamma, S1);

  // qkv (window-permuted outputs): q->S2, k->kwin, v->vwin. S0 (sc2) now dead.
  k_gemm2<0, 0, 0, 1><<<dim3(6, 512), 256, 0, stream>>>(S1, wb_qkv, nullptr, nullptr,
                                                        S2, kwin, vwin, 65536, 768, 256);

  // window attention (permuted layout) -> S0 ; spat proj S0 -> S2 (rows stay permuted)
  k_win_mfma<<<dim3(256, 4), 256, 0, stream>>>(S2, kwin, vwin, S0);
  k_gemm2<0, 0, 0, 0><<<dim3(2, 512), 256, 0, stream>>>(S0, wb_sp, nullptr, nullptr,
                                                        S2, nullptr, nullptr, 65536, 256, 256);

  // final: h in xr (S1, rolled NHWC); out2 in S2 (rolled NHWC, window-permuted rows)
  k_final2<<<dim3(256, 8, 4), 256, 0, stream>>>(S1, S2, dout);
}